// Round 9
// baseline (836.302 us; speedup 1.0000x reference)
//
#include <hip/hip_runtime.h>
#include <cstdint>
#include <cstddef>

#define BB 1024
#define AA 200
#define DD 128
#define HH 8
#define N3 384

typedef unsigned short u16;
typedef unsigned int u32;
typedef __attribute__((ext_vector_type(8))) short bf16x8;
typedef __attribute__((ext_vector_type(4))) short bf16x4;
typedef __attribute__((ext_vector_type(4))) float f32x4;

// 16x16x16 bf16 MFMA (A/B: 4 bf16 = 2 VGPRs; C/D: 4 f32). Host pass has no
// amdgcn builtins -> stub (host never executes device code, only parses it).
#if defined(__HIP_DEVICE_COMPILE__)
  #if __has_builtin(__builtin_amdgcn_mfma_f32_16x16x16_bf16)
    #define MFMA16(a,b,c) __builtin_amdgcn_mfma_f32_16x16x16_bf16(a,b,c,0,0,0)
  #else
    #define MFMA16(a,b,c) __builtin_amdgcn_mfma_f32_16x16x16bf16_1k(a,b,c,0,0,0)
  #endif
#else
  #define MFMA16(a,b,c) (c)
#endif

__device__ __forceinline__ float bf2f(u16 v){ return __uint_as_float(((u32)v) << 16); }
__device__ __forceinline__ u16 f2bf(float f){
  u32 u = __float_as_uint(f);
  u32 r = u + 0x7fffu + ((u >> 16) & 1u);
  return (u16)(r >> 16);
}
__device__ __forceinline__ bf16x8 pack8(float4 a, float4 b){
  bf16x8 o;
  o[0] = (short)f2bf(a.x); o[1] = (short)f2bf(a.y);
  o[2] = (short)f2bf(a.z); o[3] = (short)f2bf(a.w);
  o[4] = (short)f2bf(b.x); o[5] = (short)f2bf(b.y);
  o[6] = (short)f2bf(b.z); o[7] = (short)f2bf(b.w);
  return o;
}

// ---------------- K0: copy old_action to out (as float) + build rank ----------------
__global__ void k_act_rank(const int* __restrict__ oa, float* __restrict__ out0,
                           int* __restrict__ rank){
  int m = blockIdx.x * 256 + threadIdx.x;
  if (m >= BB*AA) return;
  int v = oa[m];
  out0[m] = (float)v;
  int b = m / AA;
  int j = m - b*AA;
  rank[b*AA + v] = j;
}

// ---------------- K0b: transpose+cast weights to bf16 [n][k] ----------------
__global__ void k_prep(const float* __restrict__ Wn, const float* __restrict__ Ws,
                       const float* __restrict__ Wo,
                       u16* __restrict__ WnT, u16* __restrict__ WsT,
                       u16* __restrict__ WoT){
  int idx = blockIdx.x * 256 + threadIdx.x;
  if (idx < 49152){                       // WnT: [384][128]
    int n = idx >> 7, k = idx & 127;
    WnT[idx] = f2bf(Wn[k*N3 + n]);
  } else if (idx < 65536){                // WsT: [128][128]
    int j = idx - 49152;
    int n = j >> 7, k = j & 127;
    WsT[j] = f2bf(Ws[k*DD + n]);
  } else if (idx < 81920){                // WoT: [128][128]
    int j = idx - 65536;
    int n = j >> 7, k = j & 127;
    WoT[j] = f2bf(Wo[k*DD + n]);
  }
}

// ---------------- K1: fixed_ctx = mean_a(E[b]) @ W_fixed ----------------
__global__ void k_fixed(const float* __restrict__ E, const float* __restrict__ Wf,
                        float* __restrict__ fixedc){
  int b = blockIdx.x;
  int d = threadIdx.x;              // 128 threads
  __shared__ float ge[DD];
  const float* Eb = E + (size_t)b*AA*DD;
  float s = 0.f;
  for (int a = 0; a < AA; ++a) s += Eb[a*DD + d];
  ge[d] = s * (1.0f/AA);
  __syncthreads();
  float acc = 0.f;
  for (int k = 0; k < DD; ++k) acc = fmaf(ge[k], Wf[k*DD + d], acc);
  fixedc[b*DD + d] = acc;
}

// ---------------- K2a: proj = E @ W_node via MFMA (block 128x128, wave 32x128) ----------------
__global__ __launch_bounds__(256) void k_proj_mfma(const float* __restrict__ E,
                                                   const u16* __restrict__ WnT,
                                                   u16* __restrict__ proj){
  const int t = threadIdx.x;
  const int w = t >> 6, L = t & 63;
  const int l16 = L & 15, lq = L >> 4;
  const int m0 = blockIdx.x * 128;
  const int n0 = blockIdx.y * 128;
  const int row0 = m0 + w*32;

  f32x4 acc[2][8] = {};
  const float* Arow0 = E + (size_t)(row0 + l16)*DD;
  const float* Arow1 = Arow0 + (size_t)16*DD;
  #pragma unroll
  for (int ks = 0; ks < 4; ++ks){
    int ko = ks*32 + lq*8;
    bf16x8 a0 = pack8(*(const float4*)(Arow0 + ko), *(const float4*)(Arow0 + ko + 4));
    bf16x8 a1 = pack8(*(const float4*)(Arow1 + ko), *(const float4*)(Arow1 + ko + 4));
    #pragma unroll
    for (int nt = 0; nt < 8; ++nt){
      union { uint4 u; bf16x8 v; } bb;
      bb.u = *(const uint4*)(WnT + (size_t)(n0 + nt*16 + l16)*DD + ko);
      acc[0][nt] = __builtin_amdgcn_mfma_f32_16x16x32_bf16(a0, bb.v, acc[0][nt], 0, 0, 0);
      acc[1][nt] = __builtin_amdgcn_mfma_f32_16x16x32_bf16(a1, bb.v, acc[1][nt], 0, 0, 0);
    }
  }
  #pragma unroll
  for (int mt = 0; mt < 2; ++mt)
    #pragma unroll
    for (int r = 0; r < 4; ++r){
      int row = row0 + mt*16 + lq*4 + r;
      u16* dst = proj + (size_t)row*N3 + n0;
      #pragma unroll
      for (int nt = 0; nt < 8; ++nt)
        dst[nt*16 + l16] = f2bf(acc[mt][nt][r]);
    }
}

// ---------------- K2b: query = (fixed_ctx + gather(E,prev) @ W_step) * 0.25 via MFMA ----------------
// NOTE: 1/sqrt(dh)=0.25 folded into the stored query (qhg consumed only by k_attn QK^T).
__global__ __launch_bounds__(256) void k_query_mfma(const float* __restrict__ E,
                                                    const int* __restrict__ oa,
                                                    const float* __restrict__ Wp,
                                                    const u16* __restrict__ WsT,
                                                    const float* __restrict__ fixedc,
                                                    u16* __restrict__ qhg){
  const int t = threadIdx.x;
  const int w = t >> 6, L = t & 63;
  const int l16 = L & 15, lq = L >> 4;
  const int m0 = blockIdx.x * 128;
  const int row0 = m0 + w*32;

  const float* src[2];
  #pragma unroll
  for (int mt = 0; mt < 2; ++mt){
    int q = row0 + mt*16 + l16;
    int b = q / AA, i = q - b*AA;
    src[mt] = (i == 0) ? Wp : (E + (size_t)(b*AA + oa[b*AA + i - 1])*DD);
  }

  f32x4 acc[2][8] = {};
  #pragma unroll
  for (int ks = 0; ks < 4; ++ks){
    int ko = ks*32 + lq*8;
    bf16x8 a0 = pack8(*(const float4*)(src[0] + ko), *(const float4*)(src[0] + ko + 4));
    bf16x8 a1 = pack8(*(const float4*)(src[1] + ko), *(const float4*)(src[1] + ko + 4));
    #pragma unroll
    for (int nt = 0; nt < 8; ++nt){
      union { uint4 u; bf16x8 v; } bb;
      bb.u = *(const uint4*)(WsT + (size_t)(nt*16 + l16)*DD + ko);
      acc[0][nt] = __builtin_amdgcn_mfma_f32_16x16x32_bf16(a0, bb.v, acc[0][nt], 0, 0, 0);
      acc[1][nt] = __builtin_amdgcn_mfma_f32_16x16x32_bf16(a1, bb.v, acc[1][nt], 0, 0, 0);
    }
  }
  #pragma unroll
  for (int mt = 0; mt < 2; ++mt)
    #pragma unroll
    for (int r = 0; r < 4; ++r){
      int row = row0 + mt*16 + lq*4 + r;
      int b = row / AA;
      const float* fc = fixedc + (size_t)b*DD;
      u16* dst = qhg + (size_t)row*DD;
      #pragma unroll
      for (int nt = 0; nt < 8; ++nt)
        dst[nt*16 + l16] = f2bf((acc[mt][nt][r] + fc[nt*16 + l16]) * 0.25f);
    }
}

// ---------------- K3: MFMA attention, S^T formulation ----------------
// S^T = K Q^T (A=K, B=Q): C-layout lane=i(col), regs=a(row).
//  - softmax over a: in-register (51 ops) + 2 cross-quad shfls
//  - P stays in registers: S^T e-values are exactly the 16x16x16 B-operand
//    layout (k=lq*4+r) -> PV = 13 x MFMA16 with A = VT rows. No P LDS.
//  - H^T output: lane=i, regs=d consecutive -> one 8-B store.
// Grid (h, b): 8 head-blocks of one b dispatch-adjacent -> K/V L2 reuse.
#define KSTR 24    // u16 stride: 48-B rows, 16-B aligned
#define VSTR 232   // u16 stride for VT
__global__ __launch_bounds__(256, 4) void k_attn(const u16* __restrict__ proj,
                                                 const int* __restrict__ rank,
                                                 u16* __restrict__ qhg){
  __shared__ __align__(16) u16 KL[208*KSTR];     // [a][d], rows >=200 zero
  __shared__ __align__(16) u16 VT[16*VSTR];      // [d][a], cols >=200 zero
  __shared__ __align__(16) int rankL[208];
  const int h = blockIdx.x;
  const int b = blockIdx.y;
  const int t = threadIdx.x;
  const int w = t >> 6, L = t & 63;
  const int l16 = L & 15, lq = L >> 4;

  // zero only tail regions disjoint from staging (no zero-vs-stage race)
  if (t < 192) KL[200*KSTR + t] = 0;                 // rows 200..207
  for (int idx = t; idx < 16*32; idx += 256){        // VT cols 200..231
    int d = idx >> 5, c = idx & 31;
    VT[d*VSTR + 200 + c] = 0;
  }
  if (t < 208) rankL[t] = (t < AA) ? rank[b*AA + t] : -1;

  // stage K rows + V transposed (cooperative; each thread owns row t)
  if (t < AA){
    const u16* src = proj + ((size_t)(b*AA + t))*N3 + h*16;   // gK
    uint4 k0 = *(const uint4*)(src);
    uint4 k1 = *(const uint4*)(src + 8);
    *(uint4*)&KL[t*KSTR]     = k0;
    *(uint4*)&KL[t*KSTR + 8] = k1;
    const u16* sv = src + 128;                                // gV
    u16 d16[16];
    *(uint4*)(d16)   = *(const uint4*)(sv);
    *(uint4*)(d16+8) = *(const uint4*)(sv+8);
    #pragma unroll
    for (int d = 0; d < 16; ++d) VT[d*VSTR + t] = d16[d];
  }
  __syncthreads();

  u16* Qb = qhg + (size_t)b*AA*DD + h*16;   // Q in, H out (same rows per wave)
  const bf16x8 zf8 = {0,0,0,0,0,0,0,0};

  for (int it = w; it < 13; it += 4){
    const int i = it*16 + l16;              // this lane's column (step index)
    // B-frag: Q[i][d=lq*8+j] (d>=16 zero, i>=200 pad); Q pre-scaled by 0.25
    bf16x8 qf = zf8;
    if (lq < 2 && i < AA){
      union { uint4 u; bf16x8 v; } tmp;
      tmp.u = *(const uint4*)(Qb + (size_t)i*DD + lq*8);
      qf = tmp.v;
    }
    // S^T tiles: D[m=a_loc][n=i] ; regs r: a = at*16 + lq*4 + r
    f32x4 S[13];
    #pragma unroll
    for (int at = 0; at < 13; ++at){
      bf16x8 kf = zf8;
      if (lq < 2){
        union { uint4 u; bf16x8 v; } tmp;
        tmp.u = *(const uint4*)&KL[(at*16 + l16)*KSTR + lq*8];
        kf = tmp.v;
      }
      f32x4 z = {0.f,0.f,0.f,0.f};
      S[at] = __builtin_amdgcn_mfma_f32_16x16x32_bf16(kf, qf, z, 0, 0, 0);
    }
    // mask: a visited before step i  (pad rows have rank -1 -> always masked)
    #pragma unroll
    for (int at = 0; at < 13; ++at){
      int4 rr = *(const int4*)&rankL[at*16 + lq*4];
      S[at][0] = (rr.x < i) ? -__builtin_inff() : S[at][0];
      S[at][1] = (rr.y < i) ? -__builtin_inff() : S[at][1];
      S[at][2] = (rr.z < i) ? -__builtin_inff() : S[at][2];
      S[at][3] = (rr.w < i) ? -__builtin_inff() : S[at][3];
    }
    // column softmax: in-register over 52 a's + 2 cross-quad shfls
    float m = S[0][0];
    #pragma unroll
    for (int at = 0; at < 13; ++at)
      #pragma unroll
      for (int r = 0; r < 4; ++r) m = fmaxf(m, S[at][r]);
    m = fmaxf(m, __shfl_xor(m, 16));
    m = fmaxf(m, __shfl_xor(m, 32));
    float sum = 0.f;
    #pragma unroll
    for (int at = 0; at < 13; ++at)
      #pragma unroll
      for (int r = 0; r < 4; ++r){
        float e = __expf(S[at][r] - m);
        S[at][r] = e; sum += e;
      }
    sum += __shfl_xor(sum, 16);
    sum += __shfl_xor(sum, 32);
    const float inv = 1.0f / sum;
    // PV: H^T[d][i] = sum_a V^T[d][a] * e[a][i]; e packs (trunc) directly
    // into the 16x16x16 B-operand (n=i lane, k=lq*4+r regs).
    f32x4 acc = {0.f,0.f,0.f,0.f};
    #pragma unroll
    for (int at = 0; at < 13; ++at){
      u32 p0 = (__float_as_uint(S[at][0]) >> 16) | (__float_as_uint(S[at][1]) & 0xffff0000u);
      u32 p1 = (__float_as_uint(S[at][2]) >> 16) | (__float_as_uint(S[at][3]) & 0xffff0000u);
      union { u32 u[2]; bf16x4 v; } pf; pf.u[0] = p0; pf.u[1] = p1;
      union { uint2 u; bf16x4 v; } vf;
      vf.u = *(const uint2*)&VT[l16*VSTR + at*16 + lq*4];
      acc = MFMA16(vf.v, pf.v, acc);
    }
    // store H: lane=i, regs=d=lq*4+r consecutive -> one 8-B store
    if (i < AA){
      uint2 o;
      o.x = (u32)f2bf(acc[0]*inv) | ((u32)f2bf(acc[1]*inv) << 16);
      o.y = (u32)f2bf(acc[2]*inv) | ((u32)f2bf(acc[3]*inv) << 16);
      *(uint2*)(Qb + (size_t)i*DD + lq*4) = o;
    }
  }
}

// ---------------- K4: glimpse = heads @ W_out via MFMA -> proj cols [0..127] ----------------
__global__ __launch_bounds__(256) void k_glimpse_mfma(const u16* __restrict__ qhg,
                                                      const u16* __restrict__ WoT,
                                                      u16* __restrict__ proj){
  const int t = threadIdx.x;
  const int w = t >> 6, L = t & 63;
  const int l16 = L & 15, lq = L >> 4;
  const int m0 = blockIdx.x * 128;
  const int row0 = m0 + w*32;

  f32x4 acc[2][8] = {};
  const u16* Arow0 = qhg + (size_t)(row0 + l16)*DD;
  const u16* Arow1 = Arow0 + (size_t)16*DD;
  #pragma unroll
  for (int ks = 0; ks < 4; ++ks){
    int ko = ks*32 + lq*8;
    union { uint4 u; bf16x8 v; } a0, a1;
    a0.u = *(const uint4*)(Arow0 + ko);
    a1.u = *(const uint4*)(Arow1 + ko);
    #pragma unroll
    for (int nt = 0; nt < 8; ++nt){
      union { uint4 u; bf16x8 v; } bb;
      bb.u = *(const uint4*)(WoT + (size_t)(nt*16 + l16)*DD + ko);
      acc[0][nt] = __builtin_amdgcn_mfma_f32_16x16x32_bf16(a0.v, bb.v, acc[0][nt], 0, 0, 0);
      acc[1][nt] = __builtin_amdgcn_mfma_f32_16x16x32_bf16(a1.v, bb.v, acc[1][nt], 0, 0, 0);
    }
  }
  #pragma unroll
  for (int mt = 0; mt < 2; ++mt)
    #pragma unroll
    for (int r = 0; r < 4; ++r){
      int row = row0 + mt*16 + lq*4 + r;
      u16* dst = proj + (size_t)row*N3;
      #pragma unroll
      for (int nt = 0; nt < 8; ++nt)
        dst[nt*16 + l16] = f2bf(acc[mt][nt][r]);
    }
}

// ---------------- K5: MFMA logits: tanh -> mask -> log_softmax -> gather -> sum ----------------
__global__ __launch_bounds__(256) void k_logits(const u16* __restrict__ proj,
                                                const int* __restrict__ rank,
                                                const int* __restrict__ oa,
                                                float* __restrict__ outlps){
  __shared__ float red[4];
  const int b = blockIdx.x;
  const int t = threadIdx.x;
  const int w = t >> 6, L = t & 63;
  const int l16 = L & 15, lq = L >> 4;
  const float inv_sqrt_d = 0.08838834764831843f;  // 1/sqrt(128)

  const u16* Gbase  = proj + (size_t)b*AA*N3;       // glimpse cols [0..127]
  const u16* LKbase = Gbase + 256;                  // logit_K cols [256..383]

  int ra[13];
  #pragma unroll
  for (int at = 0; at < 13; ++at){
    int a = at*16 + l16;
    ra[at] = (a < AA) ? rank[b*AA + a] : -1;        // -1 => always masked
  }

  float lp_part = 0.f;

  for (int it = w; it < 13; it += 4){
    bf16x8 af[4];
    {
      const u16* arow = Gbase + (size_t)(it*16 + l16)*N3;
      #pragma unroll
      for (int kb = 0; kb < 4; ++kb){
        union { uint4 u; bf16x8 v; } tmp;
        tmp.u = *(const uint4*)(arow + kb*32 + lq*8);
        af[kb] = tmp.v;
      }
    }
    f32x4 S[13];
    #pragma unroll
    for (int at = 0; at < 13; ++at){
      const u16* brow = LKbase + (size_t)(at*16 + l16)*N3;
      f32x4 acc = {0.f,0.f,0.f,0.f};
      #pragma unroll
      for (int kb = 0; kb < 4; ++kb){
        union { uint4 u; bf16x8 v; } tmp;
        tmp.u = *(const uint4*)(brow + kb*32 + lq*8);
        acc = __builtin_amdgcn_mfma_f32_16x16x32_bf16(af[kb], tmp.v, acc, 0, 0, 0);
      }
      S[at] = acc;
    }
    #pragma unroll
    for (int at = 0; at < 13; ++at)
      #pragma unroll
      for (int r = 0; r < 4; ++r){
        int i = it*16 + lq*4 + r;
        float x = S[at][r] * inv_sqrt_d;
        float e = __expf(2.0f*x);
        float th = 1.0f - 2.0f/(e + 1.0f);
        S[at][r] = (ra[at] < i) ? -__builtin_inff() : 10.0f*th;
      }
    #pragma unroll
    for (int r = 0; r < 4; ++r){
      int i = it*16 + lq*4 + r;
      float m = S[0][r];
      #pragma unroll
      for (int at = 1; at < 13; ++at) m = fmaxf(m, S[at][r]);
      #pragma unroll
      for (int off = 1; off < 16; off <<= 1) m = fmaxf(m, __shfl_xor(m, off));
      float sum = 0.f;
      #pragma unroll
      for (int at = 0; at < 13; ++at) sum += __expf(S[at][r] - m);
      #pragma unroll
      for (int off = 1; off < 16; off <<= 1) sum += __shfl_xor(sum, off);
      if (i < AA){
        float lse = m + __logf(sum);
        int act = oa[b*AA + i];
        if ((act & 15) == l16){
          int at0 = act >> 4;
          #pragma unroll
          for (int at = 0; at < 13; ++at)
            if (at == at0) lp_part += S[at][r] - lse;
        }
      }
    }
  }
  #pragma unroll
  for (int off = 1; off < 64; off <<= 1) lp_part += __shfl_xor(lp_part, off);
  if (L == 0) red[w] = lp_part;
  __syncthreads();
  if (t == 0) outlps[b] = red[0] + red[1] + red[2] + red[3];
}

// ---------------- launch ----------------
extern "C" void kernel_launch(void* const* d_in, const int* in_sizes, int n_in,
                              void* d_out, int out_size, void* d_ws, size_t ws_size,
                              hipStream_t stream){
  const float* E  = (const float*)d_in[0];
  const int*   oa = (const int*)d_in[1];
  const float* Wp = (const float*)d_in[2];
  const float* Wn = (const float*)d_in[3];
  const float* Wf = (const float*)d_in[4];
  const float* Ws = (const float*)d_in[5];
  const float* Wo = (const float*)d_in[6];
  float* out = (float*)d_out;

  char* ws = (char*)d_ws;
  int*   rank   = (int*)ws;                     //   819,200 B
  float* fixedc = (float*)(ws + 819200);        //   524,288 B
  u16*   proj   = (u16*)(ws + 1343488);         // 157,286,400 B  [B][A][384] bf16
  u16*   qhg    = (u16*)(ws + 158629888);       //  52,428,800 B  [B][A][128] bf16
  u16*   WnT    = (u16*)(ws + 211058688);       //      98,304 B  [384][128] bf16
  u16*   WsT    = (u16*)(ws + 211156992);       //      32,768 B  [128][128] bf16
  u16*   WoT    = (u16*)(ws + 211189760);       //      32,768 B  [128][128] bf16
  // total workspace: 211,222,528 B

  k_act_rank<<<dim3((BB*AA)/256), 256, 0, stream>>>(oa, out, rank);
  k_prep<<<dim3(320), 256, 0, stream>>>(Wn, Ws, Wo, WnT, WsT, WoT);
  k_fixed<<<dim3(BB), 128, 0, stream>>>(E, Wf, fixedc);
  k_proj_mfma<<<dim3((BB*AA)/128, N3/128), 256, 0, stream>>>(E, WnT, proj);
  k_query_mfma<<<dim3((BB*AA)/128), 256, 0, stream>>>(E, oa, Wp, WsT, fixedc, qhg);
  k_attn<<<dim3(HH, BB), 256, 0, stream>>>(proj, rank, qhg);
  k_glimpse_mfma<<<dim3((BB*AA)/128), 256, 0, stream>>>(qhg, WoT, proj);
  k_logits<<<dim3(BB), 256, 0, stream>>>(proj, rank, oa, out + BB*AA);
}